// Round 1
// baseline (67.946 us; speedup 1.0000x reference)
//
#include <hip/hip_runtime.h>
#include <math.h>

#define N_G   1024
#define W_IMG 256
#define H_IMG 256
#define T_FR  2
// cull gaussians whose max w=exp2(e) over the row is < 2^-20 (~1e-6);
// worst case 1024 culled -> < 1e-3 total error, threshold is 2e-2.
#define CULL_E (-20.0f)

__global__ __launch_bounds__(256) void gi_render(
    const float* __restrict__ xyz,   // (3, N, 2)
    const float* __restrict__ chol,  // (3, N, 3)
    const float* __restrict__ opc,   // (3, N, 1)
    const float* __restrict__ feat,  // (N, 3)
    float* __restrict__ out)         // (T, 3, H, W)
{
    __shared__ float4 s_geo[N_G];   // {mx, A, Bdy, Kdy}
    __shared__ float4 s_col[N_G];   // {cr, cg, cb, 0}
    __shared__ int    s_count;

    const int tid = threadIdx.x;
    const int bid = blockIdx.x;
    const int t   = bid >> 8;       // frame index (0..T-1)
    const int y   = bid & 255;      // image row
    const float py = (float)y + 0.5f;

    if (tid == 0) s_count = 0;
    __syncthreads();

    // t_power: linspace(0,1,T) with T=2 -> t itself; powers [1, tt, tt^2]
    const float tt = (float)t;
    const float p1 = tt;
    const float p2 = tt * tt;
    const float L2E = 1.4426950408889634f;  // log2(e)

    // ---- Phase 1: per-gaussian params + row culling + LDS compaction ----
    #pragma unroll
    for (int g = 0; g < N_G / 256; ++g) {
        const int n = g * 256 + tid;

        // xy_t = tanh(sum_d p_d * xyz[d][n][c])
        float x0 = xyz[n*2 + 0] + xyz[(N_G + n)*2 + 0]*p1 + xyz[(2*N_G + n)*2 + 0]*p2;
        float x1 = xyz[n*2 + 1] + xyz[(N_G + n)*2 + 1]*p1 + xyz[(2*N_G + n)*2 + 1]*p2;
        float mx = 0.5f * (tanhf(x0) + 1.0f) * (float)W_IMG;
        float my = 0.5f * (tanhf(x1) + 1.0f) * (float)H_IMG;

        // chol_t = sum_d p_d * chol[d][n][c] + [0.5, 0, 0.5]
        float l1 = chol[n*3+0] + chol[(N_G+n)*3+0]*p1 + chol[(2*N_G+n)*3+0]*p2 + 0.5f;
        float l2 = chol[n*3+1] + chol[(N_G+n)*3+1]*p1 + chol[(2*N_G+n)*3+1]*p2;
        float l3 = chol[n*3+2] + chol[(N_G+n)*3+2]*p1 + chol[(2*N_G+n)*3+2]*p2 + 0.5f;

        float s11 = l1*l1;
        float s12 = l1*l2;
        float s22 = l2*l2 + l3*l3;
        float det = fmaxf(s11*s22 - s12*s12, 1e-8f);
        float inv = 1.0f / det;
        float a =  s22 * inv;
        float b = -s12 * inv;
        float c =  s11 * inv;

        // opacity = sigmoid(sum_d p_d * opc[d][n])
        float ol = opc[n] + opc[N_G + n]*p1 + opc[2*N_G + n]*p2;
        float opv = 1.0f / (1.0f + __expf(-ol));

        // exponent in log2 space: e = A*dx^2 + (Bc*dy)*dx + (C*dy^2 + K)
        float A  = -0.5f * a * L2E;
        float Bc = -b * L2E;
        float C  = -0.5f * c * L2E;
        float K  = __log2f(opv);

        float dy  = py - my;
        float Bdy = Bc * dy;
        float Kdy = fmaf(C * dy, dy, K);

        // max of concave quadratic over dx in [0.5-mx, 255.5-mx]
        float dxl = 0.5f - mx, dxr = 255.5f - mx;
        float el = fmaf(fmaf(A, dxl, Bdy), dxl, Kdy);
        float er = fmaf(fmaf(A, dxr, Bdy), dxr, Kdy);
        float emax = fmaxf(el, er);
        float dxv = -Bdy / (2.0f * A);        // NaN/inf if A==0 -> branch false
        if (dxv > dxl && dxv < dxr) {
            float ev = fmaf(fmaf(A, dxv, Bdy), dxv, Kdy);
            emax = fmaxf(emax, ev);
        }

        if (emax > CULL_E) {
            int idx = atomicAdd(&s_count, 1);
            s_geo[idx] = make_float4(mx, A, Bdy, Kdy);
            float cr = 1.0f / (1.0f + __expf(-feat[n*3+0]));
            float cg = 1.0f / (1.0f + __expf(-feat[n*3+1]));
            float cb = 1.0f / (1.0f + __expf(-feat[n*3+2]));
            s_col[idx] = make_float4(cr, cg, cb, 0.0f);
        }
    }
    __syncthreads();

    // ---- Phase 2: per-pixel accumulation over compacted list ----
    const int cnt = s_count;
    const float px = (float)tid + 0.5f;
    float accr = 0.0f, accg = 0.0f, accb = 0.0f;

    for (int i = 0; i < cnt; ++i) {
        float4 gp = s_geo[i];
        float4 gc = s_col[i];
        float dx = px - gp.x;
        float e  = fmaf(gp.y, dx*dx, fmaf(gp.z, dx, gp.w));
        float w  = __builtin_amdgcn_exp2f(e);
        accr = fmaf(w, gc.x, accr);
        accg = fmaf(w, gc.y, accg);
        accb = fmaf(w, gc.z, accb);
    }

    const int base = ((t*3) << 16) + (y << 8) + tid;  // H=W=256
    out[base            ] = fminf(fmaxf(accr, 0.0f), 1.0f);
    out[base + (1 << 16)] = fminf(fmaxf(accg, 0.0f), 1.0f);
    out[base + (2 << 16)] = fminf(fmaxf(accb, 0.0f), 1.0f);
}

extern "C" void kernel_launch(void* const* d_in, const int* in_sizes, int n_in,
                              void* d_out, int out_size, void* d_ws, size_t ws_size,
                              hipStream_t stream) {
    const float* xyz  = (const float*)d_in[0];
    const float* chol = (const float*)d_in[1];
    const float* opc  = (const float*)d_in[2];
    const float* feat = (const float*)d_in[3];
    float* out = (float*)d_out;
    // one block per (frame, row): T*H = 512 blocks, 256 threads = 1 px each
    gi_render<<<T_FR * H_IMG, 256, 0, stream>>>(xyz, chol, opc, feat, out);
}